// Round 1
// baseline (487.354 us; speedup 1.0000x reference)
//
#include <hip/hip_runtime.h>
#include <math.h>

#define BB 8
#define NN 4096
#define DD 1024
#define PP 16

static constexpr float DLOG2PI = 1881.9861160031696f; // 1024 * log(2*pi)
static constexpr float EPSC = 0.1f;

// W layout: Wmat[b][k][32] interleaved pairs: [j*2]=invS_j(k), [j*2+1]=mu_j(k)*invS_j(k)

// ---------------------------------------------------------------------------
// k_init: build Wmat + cns[b][j] = log pi - 0.5*(d log2pi + sum log S + sum mu^2/S)
// grid (16 j, 8 b), 256 threads (4 d each)
// ---------------------------------------------------------------------------
__global__ __launch_bounds__(256) void k_init(const float* __restrict__ m,
                                              const float* __restrict__ V_,
                                              float* __restrict__ Wmat,
                                              float* __restrict__ cns)
{
    int j = blockIdx.x, b = blockIdx.y;
    int tid = threadIdx.x;
    __shared__ float red[512];
    int d0 = tid * 4;
    float4 m4 = *(const float4*)(m + j * DD + d0);
    float4 v4 = *(const float4*)(V_ + j * DD + d0);
    float mv[4] = {m4.x, m4.y, m4.z, m4.w};
    float vv[4] = {v4.x, v4.y, v4.z, v4.w};
    float* Wb = Wmat + (size_t)b * (DD * 32);
    float llog = 0.f, lmq = 0.f;
#pragma unroll
    for (int c = 0; c < 4; c++) {
        float V = EPSC * log1pf(expf(vv[c]));
        float inv = 1.0f / V;
        int d = d0 + c;
        Wb[d * 32 + j * 2] = inv;
        Wb[d * 32 + j * 2 + 1] = mv[c] * inv;
        llog += logf(V);
        lmq += mv[c] * mv[c] * inv;
    }
    red[tid] = llog; red[256 + tid] = lmq;
    __syncthreads();
    for (int s = 128; s > 0; s >>= 1) {
        if (tid < s) { red[tid] += red[tid + s]; red[256 + tid] += red[256 + tid + s]; }
        __syncthreads();
    }
    if (tid == 0)
        cns[b * PP + j] = logf(1.0f / 16.0f) - 0.5f * (DLOG2PI + red[0] + red[256]);
}

// ---------------------------------------------------------------------------
// k_estep (FUSED): full-d jll for 64 rows + in-kernel softmax -> qq.
// grid (64 tiles of 64 rows, 8 b) = 512 blocks (2/CU), 256 threads.
// micro-tile: 2 rows (2ty, 2ty+1) x 2 j (2tx, 2tx+1), both S1 and S2.
// Register-prefetch double buffering: next 32-k strip issued into regs before
// compute, stored to LDS after the barrier (global latency hides under FMAs).
// Asub/Wsub pad 36: float4-aligned, <=2-way bank aliasing (free).
// ---------------------------------------------------------------------------
__global__ __launch_bounds__(256) void k_estep(const float* __restrict__ X,
                                               const float* __restrict__ Wmat,
                                               const float* __restrict__ mask,
                                               const float* __restrict__ cns,
                                               float* __restrict__ qq)
{
    int tile = blockIdx.x, b = blockIdx.y;
    int n0 = tile * 64;
    const float* Xb = X + ((size_t)b * NN + n0) * DD;
    const float* Wb = Wmat + (size_t)b * (DD * 32);
    __shared__ float Asub[64 * 36];   // 9.2 KB
    __shared__ float Wsub[32 * 36];   // 4.6 KB
    __shared__ float sjl[64 * 17];    // 4.3 KB
    __shared__ float cs[16];
    int tid = threadIdx.x;
    int tx = tid & 7, ty = tid >> 3;              // tx: j pair; ty: row pair
    if (tid < 16) cs[tid] = cns[b * PP + tid];

    // staging map: float4 id g -> row g>>3, kq (g&7)*4 ; thread owns g=tid, g=tid+256
    int srow = tid >> 3;                          // 0..31 (and +32)
    int skq  = (tid & 7) << 2;

    float4 pa0, pa1, pw;
    pa0 = *(const float4*)(Xb + (size_t)srow * DD + skq);
    pa1 = *(const float4*)(Xb + (size_t)(srow + 32) * DD + skq);
    pw  = *(const float4*)(Wb + (size_t)srow * 32 + skq);
    *(float4*)(Asub + srow * 36 + skq) = pa0;
    *(float4*)(Asub + (srow + 32) * 36 + skq) = pa1;
    *(float4*)(Wsub + srow * 36 + skq) = pw;

    float m1[2][2] = {{0.f,0.f},{0.f,0.f}};   // main S1 acc
    float m2[2][2] = {{0.f,0.f},{0.f,0.f}};   // main S2 acc
    __syncthreads();

    for (int kk = 0; kk < DD; kk += 32) {
        if (kk + 32 < DD) {   // issue next strip early (overlaps compute below)
            pa0 = *(const float4*)(Xb + (size_t)srow * DD + kk + 32 + skq);
            pa1 = *(const float4*)(Xb + (size_t)(srow + 32) * DD + kk + 32 + skq);
            pw  = *(const float4*)(Wb + (size_t)(kk + 32 + srow) * 32 + skq);
        }
        float s1[2][2] = {{0.f,0.f},{0.f,0.f}};
        float s2[2][2] = {{0.f,0.f},{0.f,0.f}};
#pragma unroll 4
        for (int k = 0; k < 32; k += 2) {
            float4 w0 = *(const float4*)(Wsub + k * 36 + tx * 4);
            float4 w1 = *(const float4*)(Wsub + (k + 1) * 36 + tx * 4);
            float2 a0 = *(const float2*)(Asub + (2 * ty) * 36 + k);
            float2 a1 = *(const float2*)(Asub + (2 * ty + 1) * 36 + k);
            float q0 = a0.x * a0.x, q1 = a1.x * a1.x;
            s1[0][0] += q0 * w0.x; s2[0][0] += a0.x * w0.y; s1[0][1] += q0 * w0.z; s2[0][1] += a0.x * w0.w;
            s1[1][0] += q1 * w0.x; s2[1][0] += a1.x * w0.y; s1[1][1] += q1 * w0.z; s2[1][1] += a1.x * w0.w;
            float q2 = a0.y * a0.y, q3 = a1.y * a1.y;
            s1[0][0] += q2 * w1.x; s2[0][0] += a0.y * w1.y; s1[0][1] += q2 * w1.z; s2[0][1] += a0.y * w1.w;
            s1[1][0] += q3 * w1.x; s2[1][0] += a1.y * w1.y; s1[1][1] += q3 * w1.z; s2[1][1] += a1.y * w1.w;
        }
#pragma unroll
        for (int r = 0; r < 2; r++)
#pragma unroll
            for (int c = 0; c < 2; c++) { m1[r][c] += s1[r][c]; m2[r][c] += s2[r][c]; }
        __syncthreads();
        if (kk + 32 < DD) {
            *(float4*)(Asub + srow * 36 + skq) = pa0;
            *(float4*)(Asub + (srow + 32) * 36 + skq) = pa1;
            *(float4*)(Wsub + srow * 36 + skq) = pw;
        }
        __syncthreads();
    }

    // deposit jll partial (-0.5*S1 + S2), then per-row softmax
#pragma unroll
    for (int r = 0; r < 2; r++)
#pragma unroll
        for (int c = 0; c < 2; c++)
            sjl[(2 * ty + r) * 17 + 2 * tx + c] = -0.5f * m1[r][c] + m2[r][c];
    __syncthreads();
    if (tid < 64) {
        int n = n0 + tid;
        float jl[16];
        float mx = -3.4e38f;
#pragma unroll
        for (int j = 0; j < 16; j++) { jl[j] = sjl[tid * 17 + j] + cs[j]; mx = fmaxf(mx, jl[j]); }
        float sum = 0.f;
#pragma unroll
        for (int j = 0; j < 16; j++) { jl[j] = expf(jl[j] - mx); sum += jl[j]; }
        float r = mask[(size_t)b * NN + n] / sum;
        float* qo = qq + ((size_t)b * NN + n) * PP;
#pragma unroll
        for (int q = 0; q < 4; q++)
            *(float4*)(qo + q * 4) = make_float4(jl[q * 4 + 0] * r, jl[q * 4 + 1] * r,
                                                 jl[q * 4 + 2] * r, jl[q * 4 + 3] * r);
    }
}

// ---------------------------------------------------------------------------
// k_mstep: partial wxsum/wxxsum. grid (16 chunks of 64 cols, 8 nq of 512 rows, 8 b)
// thread: cg=4 cols, rg=rows n%16; acc[16 j][4 cols] x2 in registers.
// ---------------------------------------------------------------------------
__global__ __launch_bounds__(256) void k_mstep(const float* __restrict__ X,
                                               const float* __restrict__ qq,
                                               float* __restrict__ wxp,
                                               float* __restrict__ wxxp)
{
    int cc = blockIdx.x, nq = blockIdx.y, b = blockIdx.z;
    int tid = threadIdx.x;
    int cg = tid & 15, rg = tid >> 4;
    int col0 = cc * 64 + cg * 4;
    const float* Xb = X + ((size_t)b * NN + nq * 512) * DD;
    const float* qb = qq + ((size_t)b * NN + nq * 512) * PP;
    float aw[16][4] = {};
    float ax[16][4] = {};
    for (int i = 0; i < 32; i++) {
        int n = i * 16 + rg;
        float4 x = *(const float4*)(Xb + (size_t)n * DD + col0);
        const float4 q0 = *(const float4*)(qb + n * PP + 0);
        const float4 q1 = *(const float4*)(qb + n * PP + 4);
        const float4 q2 = *(const float4*)(qb + n * PP + 8);
        const float4 q3 = *(const float4*)(qb + n * PP + 12);
        float x2x = x.x * x.x, x2y = x.y * x.y, x2z = x.z * x.z, x2w = x.w * x.w;
        float qv[16] = {q0.x, q0.y, q0.z, q0.w, q1.x, q1.y, q1.z, q1.w,
                        q2.x, q2.y, q2.z, q2.w, q3.x, q3.y, q3.z, q3.w};
#pragma unroll
        for (int jj = 0; jj < 16; jj++) {
            float qj = qv[jj];
            aw[jj][0] += qj * x.x; aw[jj][1] += qj * x.y; aw[jj][2] += qj * x.z; aw[jj][3] += qj * x.w;
            ax[jj][0] += qj * x2x; ax[jj][1] += qj * x2y; ax[jj][2] += qj * x2z; ax[jj][3] += qj * x2w;
        }
    }
    // cross-rg reduction: red[rg][jj][68] + 4-pad per rg row (stride 548)
    __shared__ float red[16 * 548]; // 35 KB
#pragma unroll
    for (int ph = 0; ph < 4; ph++) {
        int jb = (ph & 1) * 8;
        __syncthreads();
#pragma unroll
        for (int jj = 0; jj < 8; jj++) {
            float4 v;
            if (ph < 2) v = make_float4(aw[jb + jj][0], aw[jb + jj][1], aw[jb + jj][2], aw[jb + jj][3]);
            else        v = make_float4(ax[jb + jj][0], ax[jb + jj][1], ax[jb + jj][2], ax[jb + jj][3]);
            *(float4*)(red + rg * 548 + jj * 68 + cg * 4) = v;
        }
        __syncthreads();
        float* dst = (ph < 2) ? wxp : wxxp;
#pragma unroll
        for (int o = 0; o < 2; o++) {
            int idx = tid + o * 256;
            int jj = idx >> 6, c = idx & 63;
            float s = 0.f;
#pragma unroll
            for (int g = 0; g < 16; g++) s += red[g * 548 + jj * 68 + c];
            dst[(((size_t)b * 8 + nq) * PP + jb + jj) * DD + cc * 64 + c] = s;
        }
    }
}

// ---------------------------------------------------------------------------
// k_finalize: reduce partials -> pi, mu, Sigma (d_out) and next-iter W, cns.
// grid (16 j, 8 b), 256 threads (4 d each).
// ---------------------------------------------------------------------------
__global__ __launch_bounds__(256) void k_finalize(const float* __restrict__ qq,
                                                  const float* __restrict__ wxp,
                                                  const float* __restrict__ wxxp,
                                                  const float* __restrict__ m,
                                                  const float* __restrict__ V_,
                                                  float* __restrict__ pi,
                                                  float* __restrict__ mu,
                                                  float* __restrict__ Sigma,
                                                  float* __restrict__ Wmat,
                                                  float* __restrict__ cns)
{
    int j = blockIdx.x, b = blockIdx.y;
    int tid = threadIdx.x;
    __shared__ float red[256 * 17 + 8]; // stride-17 to avoid 2-bank conflicts
    __shared__ float wsr[16];
    __shared__ float sden;
    const float* qb = qq + (size_t)b * NN * PP;
    float ws[16] = {0,0,0,0,0,0,0,0,0,0,0,0,0,0,0,0};
    for (int i = 0; i < 16; i++) {
        int n = tid + i * 256;
        const float4 q0 = *(const float4*)(qb + (size_t)n * PP + 0);
        const float4 q1 = *(const float4*)(qb + (size_t)n * PP + 4);
        const float4 q2 = *(const float4*)(qb + (size_t)n * PP + 8);
        const float4 q3 = *(const float4*)(qb + (size_t)n * PP + 12);
        ws[0] += q0.x; ws[1] += q0.y; ws[2] += q0.z; ws[3] += q0.w;
        ws[4] += q1.x; ws[5] += q1.y; ws[6] += q1.z; ws[7] += q1.w;
        ws[8] += q2.x; ws[9] += q2.y; ws[10] += q2.z; ws[11] += q2.w;
        ws[12] += q3.x; ws[13] += q3.y; ws[14] += q3.z; ws[15] += q3.w;
    }
#pragma unroll
    for (int jj = 0; jj < 16; jj++) red[tid * 17 + jj] = ws[jj];
    __syncthreads();
    if (tid < 16) {
        float s = 0.f;
        for (int t = 0; t < 256; t++) s += red[t * 17 + tid];
        wsr[tid] = s + 1.0f; // + TAU
    }
    __syncthreads();
    if (tid == 0) {
        float dd = 0.f;
#pragma unroll
        for (int jj = 0; jj < 16; jj++) dd += wsr[jj];
        sden = dd;
    }
    __syncthreads();
    float rws = 1.0f / wsr[j];
    float pij = wsr[j] / sden;
    int d0 = tid * 4;
    float wxa[4] = {0, 0, 0, 0}, wxxa[4] = {0, 0, 0, 0};
#pragma unroll
    for (int g = 0; g < 8; g++) {
        const float4 a = *(const float4*)(wxp + (((size_t)b * 8 + g) * PP + j) * DD + d0);
        wxa[0] += a.x; wxa[1] += a.y; wxa[2] += a.z; wxa[3] += a.w;
        const float4 c2 = *(const float4*)(wxxp + (((size_t)b * 8 + g) * PP + j) * DD + d0);
        wxxa[0] += c2.x; wxxa[1] += c2.y; wxxa[2] += c2.z; wxxa[3] += c2.w;
    }
    float4 m4 = *(const float4*)(m + j * DD + d0);
    float4 v4 = *(const float4*)(V_ + j * DD + d0);
    float mvv[4] = {m4.x, m4.y, m4.z, m4.w};
    float vvv[4] = {v4.x, v4.y, v4.z, v4.w};
    float muo[4], sgo[4];
    float llog = 0.f, lmq = 0.f;
    float* Wb = Wmat + (size_t)b * (DD * 32);
#pragma unroll
    for (int c = 0; c < 4; c++) {
        float V = EPSC * log1pf(expf(vvv[c]));
        float muv = (wxa[c] + mvv[c]) * rws;                       // tau = 1
        float Sg = (wxxa[c] + V + mvv[c] * mvv[c]) * rws - muv * muv;
        float inv = 1.0f / Sg;
        muo[c] = muv; sgo[c] = Sg;
        int d = d0 + c;
        Wb[d * 32 + j * 2] = inv;
        Wb[d * 32 + j * 2 + 1] = muv * inv;
        llog += logf(Sg);
        lmq += muv * muv * inv;
    }
    *(float4*)(mu + ((size_t)b * PP + j) * DD + d0) = make_float4(muo[0], muo[1], muo[2], muo[3]);
    *(float4*)(Sigma + ((size_t)b * PP + j) * DD + d0) = make_float4(sgo[0], sgo[1], sgo[2], sgo[3]);
    red[tid] = llog; red[4096 + tid] = lmq;
    __syncthreads();
    for (int s = 128; s > 0; s >>= 1) {
        if (tid < s) { red[tid] += red[tid + s]; red[4096 + tid] += red[4096 + tid + s]; }
        __syncthreads();
    }
    if (tid == 0) {
        pi[b * PP + j] = pij;
        cns[b * PP + j] = logf(pij) - 0.5f * (DLOG2PI + red[0] + red[4096]);
    }
}

extern "C" void kernel_launch(void* const* d_in, const int* in_sizes, int n_in,
                              void* d_out, int out_size, void* d_ws, size_t ws_size,
                              hipStream_t stream)
{
    (void)in_sizes; (void)n_in; (void)out_size; (void)ws_size;
    const float* data = (const float*)d_in[0];
    const float* mask = (const float*)d_in[1];
    const float* m    = (const float*)d_in[2];
    const float* V_   = (const float*)d_in[3];

    float* out = (float*)d_out;
    float* pi  = out;                       // 128
    float* mu  = out + 128;                 // 131072
    float* Sg  = out + 128 + 131072;        // 131072
    float* qq  = out + 128 + 2 * 131072;    // 524288

    float* ws    = (float*)d_ws;
    float* Wmat  = ws;                        // 8*1024*32            = 262144
    float* cns   = ws + 262144;               // 128
    float* wxp   = ws + 262272;               // 8*8*16*1024          = 1048576
    float* wxxp  = ws + 262272 + 1048576;

    k_init<<<dim3(16, 8), 256, 0, stream>>>(m, V_, Wmat, cns);
    for (int it = 0; it < 3; it++) {
        k_estep<<<dim3(64, 8), 256, 0, stream>>>(data, Wmat, mask, cns, qq);
        k_mstep<<<dim3(16, 8, 8), 256, 0, stream>>>(data, qq, wxp, wxxp);
        k_finalize<<<dim3(16, 8), 256, 0, stream>>>(qq, wxp, wxxp, m, V_, pi, mu, Sg, Wmat, cns);
    }
}

// Round 2
// 475.018 us; speedup vs baseline: 1.0260x; 1.0260x over previous
//
#include <hip/hip_runtime.h>
#include <math.h>

#define BB 8
#define NN 4096
#define DD 1024
#define PP 16

static constexpr float DLOG2PI = 1881.9861160031696f; // 1024 * log(2*pi)
static constexpr float EPSC = 0.1f;

// W layout: Wmat[b][k][32] interleaved pairs: [j*2]=invS_j(k), [j*2+1]=mu_j(k)*invS_j(k)

// ---------------------------------------------------------------------------
// k_init: build Wmat + cns[b][j] = log pi - 0.5*(d log2pi + sum log S + sum mu^2/S)
// grid (16 j, 8 b), 256 threads (4 d each)
// ---------------------------------------------------------------------------
__global__ __launch_bounds__(256) void k_init(const float* __restrict__ m,
                                              const float* __restrict__ V_,
                                              float* __restrict__ Wmat,
                                              float* __restrict__ cns)
{
    int j = blockIdx.x, b = blockIdx.y;
    int tid = threadIdx.x;
    __shared__ float red[512];
    int d0 = tid * 4;
    float4 m4 = *(const float4*)(m + j * DD + d0);
    float4 v4 = *(const float4*)(V_ + j * DD + d0);
    float mv[4] = {m4.x, m4.y, m4.z, m4.w};
    float vv[4] = {v4.x, v4.y, v4.z, v4.w};
    float* Wb = Wmat + (size_t)b * (DD * 32);
    float llog = 0.f, lmq = 0.f;
#pragma unroll
    for (int c = 0; c < 4; c++) {
        float V = EPSC * log1pf(expf(vv[c]));
        float inv = 1.0f / V;
        int d = d0 + c;
        Wb[d * 32 + j * 2] = inv;
        Wb[d * 32 + j * 2 + 1] = mv[c] * inv;
        llog += logf(V);
        lmq += mv[c] * mv[c] * inv;
    }
    red[tid] = llog; red[256 + tid] = lmq;
    __syncthreads();
    for (int s = 128; s > 0; s >>= 1) {
        if (tid < s) { red[tid] += red[tid + s]; red[256 + tid] += red[256 + tid + s]; }
        __syncthreads();
    }
    if (tid == 0)
        cns[b * PP + j] = logf(1.0f / 16.0f) - 0.5f * (DLOG2PI + red[0] + red[256]);
}

// ---------------------------------------------------------------------------
// k_estep_part: 128 rows x 16 j x 256 k partial of (-0.5*S1 + S2) -> epart
// grid (32 tiles, 4 ks, 8 b) = 1024 blocks (4/CU), 256 threads.
// micro-tile: 4 rows x 2 j (both S1,S2).
// Asub_T TRANSPOSED [k][row], stride 132 (float4-aligned): inner loop reads
// the 4 micro-tile rows as ONE ds_read_b128 (2 LDS ops/k instead of 5).
// Staging writes are 4 scalar b32 per float4 (same count as before; <=4-way
// bank alias). Register prefetch: next strip's global loads issued before
// compute, stored to LDS after the barrier (HBM latency hides under FMAs).
// ---------------------------------------------------------------------------
__global__ __launch_bounds__(256) void k_estep_part(const float* __restrict__ X,
                                                    const float* __restrict__ Wmat,
                                                    float* __restrict__ epart)
{
    int tile = blockIdx.x, ks = blockIdx.y, b = blockIdx.z;
    int n0 = tile * 128, k0 = ks * 256;
    const float* Xb = X + ((size_t)b * NN + n0) * DD + k0;
    const float* Wb = Wmat + (size_t)b * (DD * 32) + (size_t)k0 * 32;
    __shared__ float AsubT[32 * 132];  // [k][row], 16.9 KB
    __shared__ float Wsub[32 * 36];    // 4.6 KB
    int tid = threadIdx.x;
    int tx = tid & 7, ty = tid >> 3;   // tx: j-pair 2tx,2tx+1 ; ty: row group (4 rows)

    // staging map: float4 g -> row g>>3 (0..127 over i), kq (g&7)*4
    int srow = tid >> 3;               // base row 0..31 (i adds 32 each)
    int skq  = (tid & 7) << 2;
    int swk  = tid >> 3;               // Wsub k   (0..31)
    int swc  = (tid & 7) << 2;         // Wsub col (0,4,..28)

    float4 pa[4], pw;
#pragma unroll
    for (int i = 0; i < 4; i++)
        pa[i] = *(const float4*)(Xb + (size_t)(srow + i * 32) * DD + skq);
    pw = *(const float4*)(Wb + (size_t)swk * 32 + swc);
#pragma unroll
    for (int i = 0; i < 4; i++) {
        int row = srow + i * 32;
        float v[4] = {pa[i].x, pa[i].y, pa[i].z, pa[i].w};
#pragma unroll
        for (int c = 0; c < 4; c++) AsubT[(skq + c) * 132 + row] = v[c];
    }
    *(float4*)(Wsub + swk * 36 + swc) = pw;

    float acc1[4][2] = {{0.f,0.f},{0.f,0.f},{0.f,0.f},{0.f,0.f}};
    float acc2[4][2] = {{0.f,0.f},{0.f,0.f},{0.f,0.f},{0.f,0.f}};
    __syncthreads();

    for (int kk = 0; kk < 256; kk += 32) {
        if (kk + 32 < 256) {  // issue next strip early; overlaps compute below
#pragma unroll
            for (int i = 0; i < 4; i++)
                pa[i] = *(const float4*)(Xb + (size_t)(srow + i * 32) * DD + kk + 32 + skq);
            pw = *(const float4*)(Wb + (size_t)(kk + 32 + swk) * 32 + swc);
        }
#pragma unroll 8
        for (int k = 0; k < 32; k++) {
            float4 w = *(const float4*)(Wsub + k * 36 + tx * 4);
            float4 a = *(const float4*)(AsubT + k * 132 + ty * 4);
            float s0 = a.x * a.x, s1 = a.y * a.y, s2 = a.z * a.z, s3 = a.w * a.w;
            acc1[0][0] += s0 * w.x; acc2[0][0] += a.x * w.y; acc1[0][1] += s0 * w.z; acc2[0][1] += a.x * w.w;
            acc1[1][0] += s1 * w.x; acc2[1][0] += a.y * w.y; acc1[1][1] += s1 * w.z; acc2[1][1] += a.y * w.w;
            acc1[2][0] += s2 * w.x; acc2[2][0] += a.z * w.y; acc1[2][1] += s2 * w.z; acc2[2][1] += a.z * w.w;
            acc1[3][0] += s3 * w.x; acc2[3][0] += a.w * w.y; acc1[3][1] += s3 * w.z; acc2[3][1] += a.w * w.w;
        }
        __syncthreads();
        if (kk + 32 < 256) {
#pragma unroll
            for (int i = 0; i < 4; i++) {
                int row = srow + i * 32;
                float v[4] = {pa[i].x, pa[i].y, pa[i].z, pa[i].w};
#pragma unroll
                for (int c = 0; c < 4; c++) AsubT[(skq + c) * 132 + row] = v[c];
            }
            *(float4*)(Wsub + swk * 36 + swc) = pw;
        }
        __syncthreads();
    }
    float* ep = epart + (((size_t)ks * BB + b) * NN + n0) * PP;
#pragma unroll
    for (int r = 0; r < 4; r++) {
        float2 v = make_float2(-0.5f * acc1[r][0] + acc2[r][0],
                               -0.5f * acc1[r][1] + acc2[r][1]);
        *(float2*)(ep + (ty * 4 + r) * PP + tx * 2) = v;
    }
}

// ---------------------------------------------------------------------------
// k_ereduce: sum 4 k-partials + cns, softmax over 16 j, * mask -> qq
// grid (32 chunks of 128 rows, 8 b), 128 threads (1 row each)
// ---------------------------------------------------------------------------
__global__ __launch_bounds__(128) void k_ereduce(const float* __restrict__ epart,
                                                 const float* __restrict__ mask,
                                                 const float* __restrict__ cns,
                                                 float* __restrict__ qq)
{
    int chunk = blockIdx.x, b = blockIdx.y;
    int tid = threadIdx.x;
    int n = chunk * 128 + tid;
    __shared__ float cs[16];
    if (tid < 16) cs[tid] = cns[b * PP + tid];
    __syncthreads();
    float jl[16];
#pragma unroll
    for (int q = 0; q < 4; q++) {
        float4 v = *(const float4*)(epart + ((size_t)b * NN + n) * PP + q * 4);
        jl[q * 4 + 0] = v.x; jl[q * 4 + 1] = v.y; jl[q * 4 + 2] = v.z; jl[q * 4 + 3] = v.w;
    }
#pragma unroll
    for (int ks = 1; ks < 4; ks++) {
#pragma unroll
        for (int q = 0; q < 4; q++) {
            float4 v = *(const float4*)(epart + (((size_t)ks * BB + b) * NN + n) * PP + q * 4);
            jl[q * 4 + 0] += v.x; jl[q * 4 + 1] += v.y; jl[q * 4 + 2] += v.z; jl[q * 4 + 3] += v.w;
        }
    }
    float mx = -3.4e38f;
#pragma unroll
    for (int j = 0; j < 16; j++) { jl[j] += cs[j]; mx = fmaxf(mx, jl[j]); }
    float sum = 0.f;
#pragma unroll
    for (int j = 0; j < 16; j++) { jl[j] = expf(jl[j] - mx); sum += jl[j]; }
    float r = mask[(size_t)b * NN + n] / sum;
    float* qo = qq + ((size_t)b * NN + n) * PP;
#pragma unroll
    for (int q = 0; q < 4; q++)
        *(float4*)(qo + q * 4) = make_float4(jl[q * 4 + 0] * r, jl[q * 4 + 1] * r,
                                             jl[q * 4 + 2] * r, jl[q * 4 + 3] * r);
}

// ---------------------------------------------------------------------------
// k_mstep: partial wxsum/wxxsum. grid (16 chunks of 64 cols, 8 nq of 512 rows, 8 b)
// thread: cg=4 cols, rg=rows n%16; acc[16 j][4 cols] x2 in registers.
// ---------------------------------------------------------------------------
__global__ __launch_bounds__(256) void k_mstep(const float* __restrict__ X,
                                               const float* __restrict__ qq,
                                               float* __restrict__ wxp,
                                               float* __restrict__ wxxp)
{
    int cc = blockIdx.x, nq = blockIdx.y, b = blockIdx.z;
    int tid = threadIdx.x;
    int cg = tid & 15, rg = tid >> 4;
    int col0 = cc * 64 + cg * 4;
    const float* Xb = X + ((size_t)b * NN + nq * 512) * DD;
    const float* qb = qq + ((size_t)b * NN + nq * 512) * PP;
    float aw[16][4] = {};
    float ax[16][4] = {};
    for (int i = 0; i < 32; i++) {
        int n = i * 16 + rg;
        float4 x = *(const float4*)(Xb + (size_t)n * DD + col0);
        const float4 q0 = *(const float4*)(qb + n * PP + 0);
        const float4 q1 = *(const float4*)(qb + n * PP + 4);
        const float4 q2 = *(const float4*)(qb + n * PP + 8);
        const float4 q3 = *(const float4*)(qb + n * PP + 12);
        float x2x = x.x * x.x, x2y = x.y * x.y, x2z = x.z * x.z, x2w = x.w * x.w;
        float qv[16] = {q0.x, q0.y, q0.z, q0.w, q1.x, q1.y, q1.z, q1.w,
                        q2.x, q2.y, q2.z, q2.w, q3.x, q3.y, q3.z, q3.w};
#pragma unroll
        for (int jj = 0; jj < 16; jj++) {
            float qj = qv[jj];
            aw[jj][0] += qj * x.x; aw[jj][1] += qj * x.y; aw[jj][2] += qj * x.z; aw[jj][3] += qj * x.w;
            ax[jj][0] += qj * x2x; ax[jj][1] += qj * x2y; ax[jj][2] += qj * x2z; ax[jj][3] += qj * x2w;
        }
    }
    // cross-rg reduction: red[rg][jj][68] + 4-pad per rg row (stride 548)
    __shared__ float red[16 * 548]; // 35 KB
#pragma unroll
    for (int ph = 0; ph < 4; ph++) {
        int jb = (ph & 1) * 8;
        __syncthreads();
#pragma unroll
        for (int jj = 0; jj < 8; jj++) {
            float4 v;
            if (ph < 2) v = make_float4(aw[jb + jj][0], aw[jb + jj][1], aw[jb + jj][2], aw[jb + jj][3]);
            else        v = make_float4(ax[jb + jj][0], ax[jb + jj][1], ax[jb + jj][2], ax[jb + jj][3]);
            *(float4*)(red + rg * 548 + jj * 68 + cg * 4) = v;
        }
        __syncthreads();
        float* dst = (ph < 2) ? wxp : wxxp;
#pragma unroll
        for (int o = 0; o < 2; o++) {
            int idx = tid + o * 256;
            int jj = idx >> 6, c = idx & 63;
            float s = 0.f;
#pragma unroll
            for (int g = 0; g < 16; g++) s += red[g * 548 + jj * 68 + c];
            dst[(((size_t)b * 8 + nq) * PP + jb + jj) * DD + cc * 64 + c] = s;
        }
    }
}

// ---------------------------------------------------------------------------
// k_finalize: reduce partials -> pi, mu, Sigma (d_out) and next-iter W, cns.
// grid (16 j, 8 b), 256 threads (4 d each).
// ---------------------------------------------------------------------------
__global__ __launch_bounds__(256) void k_finalize(const float* __restrict__ qq,
                                                  const float* __restrict__ wxp,
                                                  const float* __restrict__ wxxp,
                                                  const float* __restrict__ m,
                                                  const float* __restrict__ V_,
                                                  float* __restrict__ pi,
                                                  float* __restrict__ mu,
                                                  float* __restrict__ Sigma,
                                                  float* __restrict__ Wmat,
                                                  float* __restrict__ cns)
{
    int j = blockIdx.x, b = blockIdx.y;
    int tid = threadIdx.x;
    __shared__ float red[256 * 17 + 8]; // stride-17 to avoid 2-bank conflicts
    __shared__ float wsr[16];
    __shared__ float sden;
    const float* qb = qq + (size_t)b * NN * PP;
    float ws[16] = {0,0,0,0,0,0,0,0,0,0,0,0,0,0,0,0};
    for (int i = 0; i < 16; i++) {
        int n = tid + i * 256;
        const float4 q0 = *(const float4*)(qb + (size_t)n * PP + 0);
        const float4 q1 = *(const float4*)(qb + (size_t)n * PP + 4);
        const float4 q2 = *(const float4*)(qb + (size_t)n * PP + 8);
        const float4 q3 = *(const float4*)(qb + (size_t)n * PP + 12);
        ws[0] += q0.x; ws[1] += q0.y; ws[2] += q0.z; ws[3] += q0.w;
        ws[4] += q1.x; ws[5] += q1.y; ws[6] += q1.z; ws[7] += q1.w;
        ws[8] += q2.x; ws[9] += q2.y; ws[10] += q2.z; ws[11] += q2.w;
        ws[12] += q3.x; ws[13] += q3.y; ws[14] += q3.z; ws[15] += q3.w;
    }
#pragma unroll
    for (int jj = 0; jj < 16; jj++) red[tid * 17 + jj] = ws[jj];
    __syncthreads();
    if (tid < 16) {
        float s = 0.f;
        for (int t = 0; t < 256; t++) s += red[t * 17 + tid];
        wsr[tid] = s + 1.0f; // + TAU
    }
    __syncthreads();
    if (tid == 0) {
        float dd = 0.f;
#pragma unroll
        for (int jj = 0; jj < 16; jj++) dd += wsr[jj];
        sden = dd;
    }
    __syncthreads();
    float rws = 1.0f / wsr[j];
    float pij = wsr[j] / sden;
    int d0 = tid * 4;
    float wxa[4] = {0, 0, 0, 0}, wxxa[4] = {0, 0, 0, 0};
#pragma unroll
    for (int g = 0; g < 8; g++) {
        const float4 a = *(const float4*)(wxp + (((size_t)b * 8 + g) * PP + j) * DD + d0);
        wxa[0] += a.x; wxa[1] += a.y; wxa[2] += a.z; wxa[3] += a.w;
        const float4 c2 = *(const float4*)(wxxp + (((size_t)b * 8 + g) * PP + j) * DD + d0);
        wxxa[0] += c2.x; wxxa[1] += c2.y; wxxa[2] += c2.z; wxxa[3] += c2.w;
    }
    float4 m4 = *(const float4*)(m + j * DD + d0);
    float4 v4 = *(const float4*)(V_ + j * DD + d0);
    float mvv[4] = {m4.x, m4.y, m4.z, m4.w};
    float vvv[4] = {v4.x, v4.y, v4.z, v4.w};
    float muo[4], sgo[4];
    float llog = 0.f, lmq = 0.f;
    float* Wb = Wmat + (size_t)b * (DD * 32);
#pragma unroll
    for (int c = 0; c < 4; c++) {
        float V = EPSC * log1pf(expf(vvv[c]));
        float muv = (wxa[c] + mvv[c]) * rws;                       // tau = 1
        float Sg = (wxxa[c] + V + mvv[c] * mvv[c]) * rws - muv * muv;
        float inv = 1.0f / Sg;
        muo[c] = muv; sgo[c] = Sg;
        int d = d0 + c;
        Wb[d * 32 + j * 2] = inv;
        Wb[d * 32 + j * 2 + 1] = muv * inv;
        llog += logf(Sg);
        lmq += muv * muv * inv;
    }
    *(float4*)(mu + ((size_t)b * PP + j) * DD + d0) = make_float4(muo[0], muo[1], muo[2], muo[3]);
    *(float4*)(Sigma + ((size_t)b * PP + j) * DD + d0) = make_float4(sgo[0], sgo[1], sgo[2], sgo[3]);
    red[tid] = llog; red[4096 + tid] = lmq;
    __syncthreads();
    for (int s = 128; s > 0; s >>= 1) {
        if (tid < s) { red[tid] += red[tid + s]; red[4096 + tid] += red[4096 + tid + s]; }
        __syncthreads();
    }
    if (tid == 0) {
        pi[b * PP + j] = pij;
        cns[b * PP + j] = logf(pij) - 0.5f * (DLOG2PI + red[0] + red[4096]);
    }
}

extern "C" void kernel_launch(void* const* d_in, const int* in_sizes, int n_in,
                              void* d_out, int out_size, void* d_ws, size_t ws_size,
                              hipStream_t stream)
{
    (void)in_sizes; (void)n_in; (void)out_size; (void)ws_size;
    const float* data = (const float*)d_in[0];
    const float* mask = (const float*)d_in[1];
    const float* m    = (const float*)d_in[2];
    const float* V_   = (const float*)d_in[3];

    float* out = (float*)d_out;
    float* pi  = out;                       // 128
    float* mu  = out + 128;                 // 131072
    float* Sg  = out + 128 + 131072;        // 131072
    float* qq  = out + 128 + 2 * 131072;    // 524288

    float* ws    = (float*)d_ws;
    float* Wmat  = ws;                        // 8*1024*32            = 262144
    float* cns   = ws + 262144;               // 128
    float* epart = ws + 262272;               // 4*8*4096*16          = 2097152
    float* wxp   = ws + 262272 + 2097152;     // 8*8*16*1024          = 1048576
    float* wxxp  = ws + 262272 + 2097152 + 1048576;

    k_init<<<dim3(16, 8), 256, 0, stream>>>(m, V_, Wmat, cns);
    for (int it = 0; it < 3; it++) {
        k_estep_part<<<dim3(32, 4, 8), 256, 0, stream>>>(data, Wmat, epart);
        k_ereduce<<<dim3(32, 8), 128, 0, stream>>>(epart, mask, cns, qq);
        k_mstep<<<dim3(16, 8, 8), 256, 0, stream>>>(data, qq, wxp, wxxp);
        k_finalize<<<dim3(16, 8), 256, 0, stream>>>(qq, wxp, wxxp, m, V_, pi, mu, Sg, Wmat, cns);
    }
}

// Round 3
// 459.805 us; speedup vs baseline: 1.0599x; 1.0331x over previous
//
#include <hip/hip_runtime.h>
#include <math.h>

#define BB 8
#define NN 4096
#define DD 1024
#define PP 16

static constexpr float DLOG2PI = 1881.9861160031696f; // 1024 * log(2*pi)
static constexpr float EPSC = 0.1f;

// W layout: Wmat[b][k][32] interleaved pairs: [j*2]=invS_j(k), [j*2+1]=mu_j(k)*invS_j(k)

// ---------------------------------------------------------------------------
// k_init: build Wmat + cns[b][j] = log pi - 0.5*(d log2pi + sum log S + sum mu^2/S)
// grid (16 j, 8 b), 256 threads (4 d each)
// ---------------------------------------------------------------------------
__global__ __launch_bounds__(256) void k_init(const float* __restrict__ m,
                                              const float* __restrict__ V_,
                                              float* __restrict__ Wmat,
                                              float* __restrict__ cns)
{
    int j = blockIdx.x, b = blockIdx.y;
    int tid = threadIdx.x;
    __shared__ float red[512];
    int d0 = tid * 4;
    float4 m4 = *(const float4*)(m + j * DD + d0);
    float4 v4 = *(const float4*)(V_ + j * DD + d0);
    float mv[4] = {m4.x, m4.y, m4.z, m4.w};
    float vv[4] = {v4.x, v4.y, v4.z, v4.w};
    float* Wb = Wmat + (size_t)b * (DD * 32);
    float llog = 0.f, lmq = 0.f;
#pragma unroll
    for (int c = 0; c < 4; c++) {
        float V = EPSC * log1pf(expf(vv[c]));
        float inv = 1.0f / V;
        int d = d0 + c;
        Wb[d * 32 + j * 2] = inv;
        Wb[d * 32 + j * 2 + 1] = mv[c] * inv;
        llog += logf(V);
        lmq += mv[c] * mv[c] * inv;
    }
    red[tid] = llog; red[256 + tid] = lmq;
    __syncthreads();
    for (int s = 128; s > 0; s >>= 1) {
        if (tid < s) { red[tid] += red[tid + s]; red[256 + tid] += red[256 + tid + s]; }
        __syncthreads();
    }
    if (tid == 0)
        cns[b * PP + j] = logf(1.0f / 16.0f) - 0.5f * (DLOG2PI + red[0] + red[256]);
}

// ---------------------------------------------------------------------------
// k_estep_part: 128 rows x 16 j x klen k partial of (-0.5*S1 + S2) -> epart
// grid (32 tiles, KS, 8 b), 256 threads. KS=8 -> 2048 blocks, 7 blocks/CU
// (LDS 21.5 KB), ~28 waves/CU vs 16 at KS=4. Inner loop identical to the
// round-0 known-best form (Asub row-major pad 33, Wsub pad 36, broadcast reads).
// ---------------------------------------------------------------------------
__global__ __launch_bounds__(256) void k_estep_part(const float* __restrict__ X,
                                                    const float* __restrict__ Wmat,
                                                    float* __restrict__ epart,
                                                    int klen)
{
    int tile = blockIdx.x, ks = blockIdx.y, b = blockIdx.z;
    int n0 = tile * 128, k0 = ks * klen;
    const float* Xb = X + ((size_t)b * NN + n0) * DD + k0;
    const float* Wb = Wmat + (size_t)b * (DD * 32) + (size_t)k0 * 32;
    __shared__ float Asub[128 * 33];   // 16.9 KB
    __shared__ float Wsub[32 * 36];    // 4.6 KB
    int tid = threadIdx.x;
    int tx = tid & 7, ty = tid >> 3;   // tx: j-pair 2tx,2tx+1 ; ty: row group
    float acc1[4][2] = {{0.f,0.f},{0.f,0.f},{0.f,0.f},{0.f,0.f}};
    float acc2[4][2] = {{0.f,0.f},{0.f,0.f},{0.f,0.f},{0.f,0.f}};
    for (int kk = 0; kk < klen; kk += 32) {
        __syncthreads();
#pragma unroll
        for (int i = 0; i < 4; i++) {
            int f = tid + i * 256;
            int row = f >> 3;
            int kq = (f & 7) << 2;
            float4 v = *(const float4*)(Xb + (size_t)row * DD + kk + kq);
            Asub[row * 33 + kq + 0] = v.x;
            Asub[row * 33 + kq + 1] = v.y;
            Asub[row * 33 + kq + 2] = v.z;
            Asub[row * 33 + kq + 3] = v.w;
        }
        {
            int k = tid >> 3, cq = (tid & 7) << 2;
            *(float4*)(Wsub + k * 36 + cq) = *(const float4*)(Wb + (size_t)(kk + k) * 32 + cq);
        }
        __syncthreads();
#pragma unroll 8
        for (int k = 0; k < 32; k++) {
            float4 w = *(const float4*)(Wsub + k * 36 + tx * 4);
            float a0 = Asub[(ty * 4 + 0) * 33 + k];
            float a1 = Asub[(ty * 4 + 1) * 33 + k];
            float a2 = Asub[(ty * 4 + 2) * 33 + k];
            float a3 = Asub[(ty * 4 + 3) * 33 + k];
            float s0 = a0 * a0, s1 = a1 * a1, s2 = a2 * a2, s3 = a3 * a3;
            acc1[0][0] += s0 * w.x; acc2[0][0] += a0 * w.y; acc1[0][1] += s0 * w.z; acc2[0][1] += a0 * w.w;
            acc1[1][0] += s1 * w.x; acc2[1][0] += a1 * w.y; acc1[1][1] += s1 * w.z; acc2[1][1] += a1 * w.w;
            acc1[2][0] += s2 * w.x; acc2[2][0] += a2 * w.y; acc1[2][1] += s2 * w.z; acc2[2][1] += a2 * w.w;
            acc1[3][0] += s3 * w.x; acc2[3][0] += a3 * w.y; acc1[3][1] += s3 * w.z; acc2[3][1] += a3 * w.w;
        }
    }
    float* ep = epart + (((size_t)ks * BB + b) * NN + n0) * PP;
#pragma unroll
    for (int r = 0; r < 4; r++) {
        float2 v = make_float2(-0.5f * acc1[r][0] + acc2[r][0],
                               -0.5f * acc1[r][1] + acc2[r][1]);
        *(float2*)(ep + (ty * 4 + r) * PP + tx * 2) = v;
    }
}

// ---------------------------------------------------------------------------
// k_ereduce: sum nparts k-partials + cns, softmax over 16 j, * mask -> qq
// grid (32 chunks of 128 rows, 8 b), 128 threads (1 row each)
// ---------------------------------------------------------------------------
__global__ __launch_bounds__(128) void k_ereduce(const float* __restrict__ epart,
                                                 const float* __restrict__ mask,
                                                 const float* __restrict__ cns,
                                                 float* __restrict__ qq,
                                                 int nparts)
{
    int chunk = blockIdx.x, b = blockIdx.y;
    int tid = threadIdx.x;
    int n = chunk * 128 + tid;
    __shared__ float cs[16];
    if (tid < 16) cs[tid] = cns[b * PP + tid];
    __syncthreads();
    float jl[16];
#pragma unroll
    for (int q = 0; q < 4; q++) {
        float4 v = *(const float4*)(epart + ((size_t)b * NN + n) * PP + q * 4);
        jl[q * 4 + 0] = v.x; jl[q * 4 + 1] = v.y; jl[q * 4 + 2] = v.z; jl[q * 4 + 3] = v.w;
    }
    for (int ks = 1; ks < nparts; ks++) {
#pragma unroll
        for (int q = 0; q < 4; q++) {
            float4 v = *(const float4*)(epart + (((size_t)ks * BB + b) * NN + n) * PP + q * 4);
            jl[q * 4 + 0] += v.x; jl[q * 4 + 1] += v.y; jl[q * 4 + 2] += v.z; jl[q * 4 + 3] += v.w;
        }
    }
    float mx = -3.4e38f;
#pragma unroll
    for (int j = 0; j < 16; j++) { jl[j] += cs[j]; mx = fmaxf(mx, jl[j]); }
    float sum = 0.f;
#pragma unroll
    for (int j = 0; j < 16; j++) { jl[j] = expf(jl[j] - mx); sum += jl[j]; }
    float r = mask[(size_t)b * NN + n] / sum;
    float* qo = qq + ((size_t)b * NN + n) * PP;
#pragma unroll
    for (int q = 0; q < 4; q++)
        *(float4*)(qo + q * 4) = make_float4(jl[q * 4 + 0] * r, jl[q * 4 + 1] * r,
                                             jl[q * 4 + 2] * r, jl[q * 4 + 3] * r);
}

// ---------------------------------------------------------------------------
// k_mstep: partial wxsum/wxxsum. grid (16 chunks of 64 cols, 8 nq of 512 rows, 8 b)
// thread: cg=4 cols, rg=rows n%8, jh=half of j (8 j's). acc 8x4 x2 = 64 VGPR
// (was 128): __launch_bounds__(256,4) -> 4 waves/SIMD, 16 waves/CU (was 8).
// ---------------------------------------------------------------------------
__global__ __launch_bounds__(256, 4) void k_mstep(const float* __restrict__ X,
                                                  const float* __restrict__ qq,
                                                  float* __restrict__ wxp,
                                                  float* __restrict__ wxxp)
{
    int cc = blockIdx.x, nq = blockIdx.y, b = blockIdx.z;
    int tid = threadIdx.x;
    int cg = tid & 15;           // 16 col groups of 4 cols
    int rg = (tid >> 4) & 7;     // 8 row groups
    int jh = tid >> 7;           // j half (j = jh*8 .. jh*8+7)
    int col0 = cc * 64 + cg * 4;
    const float* Xb = X + ((size_t)b * NN + nq * 512) * DD;
    const float* qb = qq + ((size_t)b * NN + nq * 512) * PP;
    float aw[8][4] = {};
    float ax[8][4] = {};
    for (int i = 0; i < 64; i++) {
        int n = i * 8 + rg;
        float4 x = *(const float4*)(Xb + (size_t)n * DD + col0);
        const float4 q0 = *(const float4*)(qb + n * PP + jh * 8);
        const float4 q1 = *(const float4*)(qb + n * PP + jh * 8 + 4);
        float x2x = x.x * x.x, x2y = x.y * x.y, x2z = x.z * x.z, x2w = x.w * x.w;
        float qv[8] = {q0.x, q0.y, q0.z, q0.w, q1.x, q1.y, q1.z, q1.w};
#pragma unroll
        for (int jj = 0; jj < 8; jj++) {
            float qj = qv[jj];
            aw[jj][0] += qj * x.x; aw[jj][1] += qj * x.y; aw[jj][2] += qj * x.z; aw[jj][3] += qj * x.w;
            ax[jj][0] += qj * x2x; ax[jj][1] += qj * x2y; ax[jj][2] += qj * x2z; ax[jj][3] += qj * x2w;
        }
    }
    // cross-rg reduction per j-half: red[rg][jj][68] (+4 pad/row, stride 548)
    __shared__ float red[8 * 548]; // 17.5 KB
#pragma unroll
    for (int ph = 0; ph < 4; ph++) {
        int jb = (ph & 1) * 8;
        __syncthreads();
        if (jh == (ph & 1)) {
#pragma unroll
            for (int jj = 0; jj < 8; jj++) {
                float4 v;
                if (ph < 2) v = make_float4(aw[jj][0], aw[jj][1], aw[jj][2], aw[jj][3]);
                else        v = make_float4(ax[jj][0], ax[jj][1], ax[jj][2], ax[jj][3]);
                *(float4*)(red + rg * 548 + jj * 68 + cg * 4) = v;
            }
        }
        __syncthreads();
        float* dst = (ph < 2) ? wxp : wxxp;
#pragma unroll
        for (int o = 0; o < 2; o++) {
            int idx = tid + o * 256;
            int jj = idx >> 6, c = idx & 63;
            float s = 0.f;
#pragma unroll
            for (int g = 0; g < 8; g++) s += red[g * 548 + jj * 68 + c];
            dst[(((size_t)b * 8 + nq) * PP + jb + jj) * DD + cc * 64 + c] = s;
        }
    }
}

// ---------------------------------------------------------------------------
// k_finalize: reduce partials -> pi, mu, Sigma (d_out) and next-iter W, cns.
// grid (16 j, 8 b), 256 threads (4 d each).
// ---------------------------------------------------------------------------
__global__ __launch_bounds__(256) void k_finalize(const float* __restrict__ qq,
                                                  const float* __restrict__ wxp,
                                                  const float* __restrict__ wxxp,
                                                  const float* __restrict__ m,
                                                  const float* __restrict__ V_,
                                                  float* __restrict__ pi,
                                                  float* __restrict__ mu,
                                                  float* __restrict__ Sigma,
                                                  float* __restrict__ Wmat,
                                                  float* __restrict__ cns)
{
    int j = blockIdx.x, b = blockIdx.y;
    int tid = threadIdx.x;
    __shared__ float red[256 * 17 + 8]; // stride-17 to avoid 2-bank conflicts
    __shared__ float wsr[16];
    __shared__ float sden;
    const float* qb = qq + (size_t)b * NN * PP;
    float ws[16] = {0,0,0,0,0,0,0,0,0,0,0,0,0,0,0,0};
    for (int i = 0; i < 16; i++) {
        int n = tid + i * 256;
        const float4 q0 = *(const float4*)(qb + (size_t)n * PP + 0);
        const float4 q1 = *(const float4*)(qb + (size_t)n * PP + 4);
        const float4 q2 = *(const float4*)(qb + (size_t)n * PP + 8);
        const float4 q3 = *(const float4*)(qb + (size_t)n * PP + 12);
        ws[0] += q0.x; ws[1] += q0.y; ws[2] += q0.z; ws[3] += q0.w;
        ws[4] += q1.x; ws[5] += q1.y; ws[6] += q1.z; ws[7] += q1.w;
        ws[8] += q2.x; ws[9] += q2.y; ws[10] += q2.z; ws[11] += q2.w;
        ws[12] += q3.x; ws[13] += q3.y; ws[14] += q3.z; ws[15] += q3.w;
    }
#pragma unroll
    for (int jj = 0; jj < 16; jj++) red[tid * 17 + jj] = ws[jj];
    __syncthreads();
    if (tid < 16) {
        float s = 0.f;
        for (int t = 0; t < 256; t++) s += red[t * 17 + tid];
        wsr[tid] = s + 1.0f; // + TAU
    }
    __syncthreads();
    if (tid == 0) {
        float dd = 0.f;
#pragma unroll
        for (int jj = 0; jj < 16; jj++) dd += wsr[jj];
        sden = dd;
    }
    __syncthreads();
    float rws = 1.0f / wsr[j];
    float pij = wsr[j] / sden;
    int d0 = tid * 4;
    float wxa[4] = {0, 0, 0, 0}, wxxa[4] = {0, 0, 0, 0};
#pragma unroll
    for (int g = 0; g < 8; g++) {
        const float4 a = *(const float4*)(wxp + (((size_t)b * 8 + g) * PP + j) * DD + d0);
        wxa[0] += a.x; wxa[1] += a.y; wxa[2] += a.z; wxa[3] += a.w;
        const float4 c2 = *(const float4*)(wxxp + (((size_t)b * 8 + g) * PP + j) * DD + d0);
        wxxa[0] += c2.x; wxxa[1] += c2.y; wxxa[2] += c2.z; wxxa[3] += c2.w;
    }
    float4 m4 = *(const float4*)(m + j * DD + d0);
    float4 v4 = *(const float4*)(V_ + j * DD + d0);
    float mvv[4] = {m4.x, m4.y, m4.z, m4.w};
    float vvv[4] = {v4.x, v4.y, v4.z, v4.w};
    float muo[4], sgo[4];
    float llog = 0.f, lmq = 0.f;
    float* Wb = Wmat + (size_t)b * (DD * 32);
#pragma unroll
    for (int c = 0; c < 4; c++) {
        float V = EPSC * log1pf(expf(vvv[c]));
        float muv = (wxa[c] + mvv[c]) * rws;                       // tau = 1
        float Sg = (wxxa[c] + V + mvv[c] * mvv[c]) * rws - muv * muv;
        float inv = 1.0f / Sg;
        muo[c] = muv; sgo[c] = Sg;
        int d = d0 + c;
        Wb[d * 32 + j * 2] = inv;
        Wb[d * 32 + j * 2 + 1] = muv * inv;
        llog += logf(Sg);
        lmq += muv * muv * inv;
    }
    *(float4*)(mu + ((size_t)b * PP + j) * DD + d0) = make_float4(muo[0], muo[1], muo[2], muo[3]);
    *(float4*)(Sigma + ((size_t)b * PP + j) * DD + d0) = make_float4(sgo[0], sgo[1], sgo[2], sgo[3]);
    red[tid] = llog; red[4096 + tid] = lmq;
    __syncthreads();
    for (int s = 128; s > 0; s >>= 1) {
        if (tid < s) { red[tid] += red[tid + s]; red[4096 + tid] += red[4096 + tid + s]; }
        __syncthreads();
    }
    if (tid == 0) {
        pi[b * PP + j] = pij;
        cns[b * PP + j] = logf(pij) - 0.5f * (DLOG2PI + red[0] + red[4096]);
    }
}

extern "C" void kernel_launch(void* const* d_in, const int* in_sizes, int n_in,
                              void* d_out, int out_size, void* d_ws, size_t ws_size,
                              hipStream_t stream)
{
    (void)in_sizes; (void)n_in; (void)out_size;
    const float* data = (const float*)d_in[0];
    const float* mask = (const float*)d_in[1];
    const float* m    = (const float*)d_in[2];
    const float* V_   = (const float*)d_in[3];

    float* out = (float*)d_out;
    float* pi  = out;                       // 128
    float* mu  = out + 128;                 // 131072
    float* Sg  = out + 128 + 131072;        // 131072
    float* qq  = out + 128 + 2 * 131072;    // 524288

    // k-split for e-step: prefer 8 (occupancy) if workspace allows, else 4.
    size_t need8 = ((size_t)262272 + (size_t)8 * BB * NN * PP
                    + (size_t)2 * BB * 8 * PP * DD) * sizeof(float);
    int KS = (ws_size >= need8) ? 8 : 4;
    int klen = DD / KS;

    float* ws    = (float*)d_ws;
    float* Wmat  = ws;                        // 8*1024*32 = 262144
    float* cns   = ws + 262144;               // 128
    float* epart = ws + 262272;               // KS*8*4096*16
    float* wxp   = epart + (size_t)KS * BB * NN * PP;
    float* wxxp  = wxp + (size_t)BB * 8 * PP * DD;

    k_init<<<dim3(16, 8), 256, 0, stream>>>(m, V_, Wmat, cns);
    for (int it = 0; it < 3; it++) {
        k_estep_part<<<dim3(32, KS, 8), 256, 0, stream>>>(data, Wmat, epart, klen);
        k_ereduce<<<dim3(32, 8), 128, 0, stream>>>(epart, mask, cns, qq, KS);
        k_mstep<<<dim3(16, 8, 8), 256, 0, stream>>>(data, qq, wxp, wxxp);
        k_finalize<<<dim3(16, 8), 256, 0, stream>>>(qq, wxp, wxxp, m, V_, pi, mu, Sg, Wmat, cns);
    }
}